// Round 1
// baseline (173.324 us; speedup 1.0000x reference)
//
#include <hip/hip_runtime.h>
#include <math.h>

#define N_SAMP 16384
#define DIN 128
#define FDIM 128
#define BINS 32
#define NEDGE 33
#define H1 1024
#define H2 512
#define NC 10

#define K1_BLOCKS 256
#define K1_ROWS 64
#define K1_THREADS 512
#define XS_STRIDE 132   // 128 + 4 pad: float4-aligned, breaks pow2 bank stride

__device__ __forceinline__ float fast_sigmoid(float z) {
    // 1/(1+e^-z); safe for any z: exp overflow -> inf -> rcp -> 0 (correct limit)
    return __builtin_amdgcn_rcpf(1.f + __expf(-z));
}
__device__ __forceinline__ float lrelu(float x) {
    return x > 0.f ? x : 0.01f * x;
}

// K1: feats = sigmoid(x @ W_feat + b_feat) for a 64-row tile, then per-block
// edge sums E_part[blk][f][e] = sum_rows sigmoid(100*s - 3.125*e), e in 0..32.
__global__ __launch_bounds__(K1_THREADS) void k1_feat_hist(
    const float* __restrict__ x, const float* __restrict__ Wf,
    const float* __restrict__ bf, float* __restrict__ E_part)
{
    __shared__ float xs[K1_ROWS * XS_STRIDE];
    const int tid  = threadIdx.x;
    const int blk  = blockIdx.x;
    const int row0 = blk * K1_ROWS;

    // ---- load x tile: 64 rows x 128 cols, float4 coalesced ----
    for (int i = tid; i < K1_ROWS * 32; i += K1_THREADS) {
        const int r  = i >> 5;
        const int c4 = i & 31;
        float4 v = *(const float4*)(x + (size_t)(row0 + r) * DIN + c4 * 4);
        *(float4*)(&xs[r * XS_STRIDE + c4 * 4]) = v;
    }
    __syncthreads();

    // ---- GEMM: thread tile = 2 rows x 8 feats ----
    const int tc = tid & 15;    // 16 feat groups of 8
    const int tr = tid >> 4;    // 32 row groups of 2
    const int f0 = tc * 8;
    const int r0 = tr * 2;

    float a00=0,a01=0,a02=0,a03=0,a04=0,a05=0,a06=0,a07=0;
    float a10=0,a11=0,a12=0,a13=0,a14=0,a15=0,a16=0,a17=0;

    #pragma unroll 4
    for (int d = 0; d < DIN; ++d) {
        const float4 wa = *(const float4*)(Wf + d * FDIM + f0);
        const float4 wb = *(const float4*)(Wf + d * FDIM + f0 + 4);
        const float xa = xs[r0 * XS_STRIDE + d];
        const float xb = xs[(r0 + 1) * XS_STRIDE + d];
        a00 = fmaf(xa, wa.x, a00); a01 = fmaf(xa, wa.y, a01);
        a02 = fmaf(xa, wa.z, a02); a03 = fmaf(xa, wa.w, a03);
        a04 = fmaf(xa, wb.x, a04); a05 = fmaf(xa, wb.y, a05);
        a06 = fmaf(xa, wb.z, a06); a07 = fmaf(xa, wb.w, a07);
        a10 = fmaf(xb, wa.x, a10); a11 = fmaf(xb, wa.y, a11);
        a12 = fmaf(xb, wa.z, a12); a13 = fmaf(xb, wa.w, a13);
        a14 = fmaf(xb, wb.x, a14); a15 = fmaf(xb, wb.y, a15);
        a16 = fmaf(xb, wb.z, a16); a17 = fmaf(xb, wb.w, a17);
    }

    const float4 bva = *(const float4*)(bf + f0);
    const float4 bvb = *(const float4*)(bf + f0 + 4);
    float s0[8], s1[8];
    s0[0]=fast_sigmoid(a00+bva.x); s0[1]=fast_sigmoid(a01+bva.y);
    s0[2]=fast_sigmoid(a02+bva.z); s0[3]=fast_sigmoid(a03+bva.w);
    s0[4]=fast_sigmoid(a04+bvb.x); s0[5]=fast_sigmoid(a05+bvb.y);
    s0[6]=fast_sigmoid(a06+bvb.z); s0[7]=fast_sigmoid(a07+bvb.w);
    s1[0]=fast_sigmoid(a10+bva.x); s1[1]=fast_sigmoid(a11+bva.y);
    s1[2]=fast_sigmoid(a12+bva.z); s1[3]=fast_sigmoid(a13+bva.w);
    s1[4]=fast_sigmoid(a14+bvb.x); s1[5]=fast_sigmoid(a15+bvb.y);
    s1[6]=fast_sigmoid(a16+bvb.z); s1[7]=fast_sigmoid(a17+bvb.w);

    __syncthreads();  // everyone done reading x before we overwrite with s
    *(float4*)(&xs[r0 * XS_STRIDE + f0])     = make_float4(s0[0],s0[1],s0[2],s0[3]);
    *(float4*)(&xs[r0 * XS_STRIDE + f0 + 4]) = make_float4(s0[4],s0[5],s0[6],s0[7]);
    *(float4*)(&xs[(r0+1) * XS_STRIDE + f0])     = make_float4(s1[0],s1[1],s1[2],s1[3]);
    *(float4*)(&xs[(r0+1) * XS_STRIDE + f0 + 4]) = make_float4(s1[4],s1[5],s1[6],s1[7]);
    __syncthreads();

    // ---- edge sums: thread owns (feat, edge-group), iterates all 64 rows ----
    const int feat   = tid & 127;
    const int eg     = tid >> 7;                    // 0..3
    const int estart = (eg == 0) ? 0 : eg * 8 + 1;  // 0,9,17,25
    const int ne     = (eg == 0) ? 9 : 8;

    float locE[9];
    #pragma unroll
    for (int j = 0; j < 9; ++j) locE[j] = 0.f;

    for (int r = 0; r < K1_ROWS; ++r) {
        const float s  = xs[r * XS_STRIDE + feat];
        const float zb = 100.f * s;
        #pragma unroll
        for (int j = 0; j < 9; ++j) {
            if (j < ne) {
                const float z = zb - 3.125f * (float)(estart + j);
                if (z > 15.f)        locE[j] += 1.f;      // saturated high (err < 3e-7)
                else if (z > -15.f)  locE[j] += fast_sigmoid(z);
                // else: contributes ~0
            }
        }
    }

    float* dst = E_part + (size_t)blk * (FDIM * NEDGE) + feat * NEDGE + estart;
    for (int j = 0; j < ne; ++j) dst[j] = locE[j];
}

// K2: E[cell] = sum over 256 block partials (coalesced: lanes = consecutive cells)
__global__ void k2_reduce_E(const float* __restrict__ E_part, float* __restrict__ E)
{
    const int cell = blockIdx.x * blockDim.x + threadIdx.x;
    if (cell >= FDIM * NEDGE) return;
    float a[16];
    #pragma unroll
    for (int k = 0; k < 16; ++k) a[k] = 0.f;
    for (int p = 0; p < K1_BLOCKS; p += 16) {
        #pragma unroll
        for (int k = 0; k < 16; ++k)
            a[k] += E_part[(size_t)(p + k) * (FDIM * NEDGE) + cell];
    }
    #pragma unroll
    for (int k = 0; k < 8; ++k) a[k] += a[k + 8];
    #pragma unroll
    for (int k = 0; k < 4; ++k) a[k] += a[k + 4];
    E[cell] = (a[0] + a[1]) + (a[2] + a[3]);
}

// K3: split-K hist @ W1. hist[i] derived on the fly from E (telescoped diff).
__global__ __launch_bounds__(256) void k3_h1_part(
    const float* __restrict__ E, const float* __restrict__ W1,
    float* __restrict__ h1_part)
{
    const int jb    = blockIdx.x & 3;    // 4 col blocks of 256
    const int chunk = blockIdx.x >> 2;   // 64 i-chunks of 64
    const int t = threadIdx.x;
    const int j = jb * 256 + t;

    __shared__ float hl[64];
    if (t < 64) {
        const int i = chunk * 64 + t;
        const int f = i >> 5, b = i & 31;
        hl[t] = (E[f * NEDGE + b] - E[f * NEDGE + b + 1]) * (1.f / (float)N_SAMP);
    }
    __syncthreads();

    float acc = 0.f;
    #pragma unroll 8
    for (int k = 0; k < 64; ++k)
        acc = fmaf(hl[k], W1[(size_t)(chunk * 64 + k) * H1 + j], acc);
    h1_part[chunk * H1 + j] = acc;
}

// K4: h1 = leaky_relu(sum partials + b1)
__global__ void k4_h1_fin(const float* __restrict__ h1_part,
                          const float* __restrict__ b1, float* __restrict__ h1)
{
    const int j = blockIdx.x * blockDim.x + threadIdx.x;  // 1024
    float acc = 0.f;
    #pragma unroll 8
    for (int c = 0; c < 64; ++c) acc += h1_part[c * H1 + j];
    h1[j] = lrelu(acc + b1[j]);
}

// K5: split-K h1 @ W2
__global__ __launch_bounds__(256) void k5_h2_part(
    const float* __restrict__ h1, const float* __restrict__ W2,
    float* __restrict__ h2_part)
{
    const int jb    = blockIdx.x & 1;    // 2 col blocks of 256
    const int chunk = blockIdx.x >> 1;   // 32 i-chunks of 32
    const int t = threadIdx.x;
    const int j = jb * 256 + t;

    __shared__ float hl[32];
    if (t < 32) hl[t] = h1[chunk * 32 + t];
    __syncthreads();

    float acc = 0.f;
    #pragma unroll
    for (int k = 0; k < 32; ++k)
        acc = fmaf(hl[k], W2[(size_t)(chunk * 32 + k) * H2 + j], acc);
    h2_part[chunk * H2 + j] = acc;
}

// K6: finalize h2, logits = h2 @ W3 + b3, softmax -> out[10]. Single block.
__global__ __launch_bounds__(512) void k6_final(
    const float* __restrict__ h2_part, const float* __restrict__ b2,
    const float* __restrict__ W3, const float* __restrict__ b3,
    float* __restrict__ out)
{
    const int t = threadIdx.x;  // 0..511
    float acc = 0.f;
    #pragma unroll
    for (int c = 0; c < 32; ++c) acc += h2_part[c * H2 + t];
    const float h2v = lrelu(acc + b2[t]);

    float lc[NC];
    #pragma unroll
    for (int c = 0; c < NC; ++c) lc[c] = h2v * W3[t * NC + c];

    #pragma unroll
    for (int off = 32; off >= 1; off >>= 1) {
        #pragma unroll
        for (int c = 0; c < NC; ++c) lc[c] += __shfl_down(lc[c], off, 64);
    }

    __shared__ float wsum[8][NC];
    const int w = t >> 6, lane = t & 63;
    if (lane == 0) {
        #pragma unroll
        for (int c = 0; c < NC; ++c) wsum[w][c] = lc[c];
    }
    __syncthreads();

    if (t == 0) {
        float logits[NC];
        float m = -1e30f;
        #pragma unroll
        for (int c = 0; c < NC; ++c) {
            float v = b3[c];
            for (int ww = 0; ww < 8; ++ww) v += wsum[ww][c];
            logits[c] = v;
            m = fmaxf(m, v);
        }
        float ssum = 0.f;
        #pragma unroll
        for (int c = 0; c < NC; ++c) { logits[c] = __expf(logits[c] - m); ssum += logits[c]; }
        const float inv = 1.f / ssum;
        #pragma unroll
        for (int c = 0; c < NC; ++c) out[c] = logits[c] * inv;
    }
}

extern "C" void kernel_launch(void* const* d_in, const int* in_sizes, int n_in,
                              void* d_out, int out_size, void* d_ws, size_t ws_size,
                              hipStream_t stream)
{
    const float* x  = (const float*)d_in[0];
    const float* Wf = (const float*)d_in[1];
    const float* bf = (const float*)d_in[2];
    const float* W1 = (const float*)d_in[3];
    const float* b1 = (const float*)d_in[4];
    const float* W2 = (const float*)d_in[5];
    const float* b2 = (const float*)d_in[6];
    const float* W3 = (const float*)d_in[7];
    const float* b3 = (const float*)d_in[8];
    float* out = (float*)d_out;

    float* ws      = (float*)d_ws;
    float* E_part  = ws;                                    // 256*4224 = 1,081,344 f
    float* E       = E_part + (size_t)K1_BLOCKS * FDIM * NEDGE;  // 4224 f
    float* h1_part = E + FDIM * NEDGE;                      // 64*1024 f
    float* h1      = h1_part + 64 * H1;                     // 1024 f
    float* h2_part = h1 + H1;                               // 32*512 f

    k1_feat_hist<<<K1_BLOCKS, K1_THREADS, 0, stream>>>(x, Wf, bf, E_part);
    k2_reduce_E<<<(FDIM * NEDGE + 255) / 256, 256, 0, stream>>>(E_part, E);
    k3_h1_part<<<256, 256, 0, stream>>>(E, W1, h1_part);
    k4_h1_fin<<<4, 256, 0, stream>>>(h1_part, b1, h1);
    k5_h2_part<<<64, 256, 0, stream>>>(h1, W2, h2_part);
    k6_final<<<1, 512, 0, stream>>>(h2_part, b2, W3, b3, out);
}

// Round 2
// 133.419 us; speedup vs baseline: 1.2991x; 1.2991x over previous
//
#include <hip/hip_runtime.h>
#include <math.h>

#define N_SAMP 16384
#define DIN 128
#define FDIM 128
#define BINS 32
#define NEDGE 33
#define CELLS (FDIM * NEDGE)   // 4224
#define H1 1024
#define H2 512
#define NC 10

#define K1_BLOCKS 512
#define K1_ROWS 32             // 512*32 = 16384 samples
#define K1_THREADS 512
#define XS_STRIDE 132          // 128+4: 16B-aligned rows (528B), breaks pow2 bank stride

#define K3_BLOCKS 256          // 16 hist rows each (4096 total)

#define EXP_3_125 22.7598950f  // e^3.125

__device__ __forceinline__ float fast_sigmoid_from_t(float t) {
    // sigma = 1/(1+t), t = e^{-z}. t==0 -> 1 (saturated hi), t==inf -> 0 (lo).
    return __builtin_amdgcn_rcpf(1.f + t);
}
__device__ __forceinline__ float lrelu(float x) { return x > 0.f ? x : 0.01f * x; }

// ---------------------------------------------------------------------------
// K1: fused  s = sigmoid(x@Wf + bf)  +  per-block edge sums
//     E_part[blk][f*33+e] = sum_rows sigma(100*s - 3.125*e)
// 512 blocks x 512 thr x 32 rows -> 16 waves/CU.
// ---------------------------------------------------------------------------
__global__ __launch_bounds__(K1_THREADS, 4) void k1_feat_hist(
    const float* __restrict__ x, const float* __restrict__ Wf,
    const float* __restrict__ bf, float* __restrict__ E_part)
{
    __shared__ float xs[K1_ROWS * XS_STRIDE];
    const int t = threadIdx.x;
    const int blk = blockIdx.x;
    const int row0 = blk * K1_ROWS;

    // ---- load x tile: 32 rows x 128 cols, float4 coalesced (2 per thread) ----
    #pragma unroll
    for (int i = 0; i < 2; ++i) {
        const int idx = t + i * K1_THREADS;
        const int r = idx >> 5, c4 = (idx & 31) << 2;
        *(float4*)&xs[r * XS_STRIDE + c4] =
            *(const float4*)(x + (size_t)(row0 + r) * DIN + c4);
    }
    __syncthreads();

    // ---- GEMM: thread tile = 2 rows x 4 feats ----
    const int tc = t & 31, tr = t >> 5;
    const int f0 = tc * 4, r0 = tr * 2;

    float4 acc0 = {0,0,0,0}, acc1 = {0,0,0,0};
    #pragma unroll 2
    for (int d = 0; d < DIN; d += 4) {
        const float4 xa = *(const float4*)&xs[r0 * XS_STRIDE + d];
        const float4 xb = *(const float4*)&xs[(r0 + 1) * XS_STRIDE + d];
        const float* wp = Wf + d * FDIM + f0;
        const float4 w0 = *(const float4*)(wp);
        const float4 w1 = *(const float4*)(wp + FDIM);
        const float4 w2 = *(const float4*)(wp + 2 * FDIM);
        const float4 w3 = *(const float4*)(wp + 3 * FDIM);
        acc0.x = fmaf(xa.x, w0.x, acc0.x); acc0.y = fmaf(xa.x, w0.y, acc0.y);
        acc0.z = fmaf(xa.x, w0.z, acc0.z); acc0.w = fmaf(xa.x, w0.w, acc0.w);
        acc0.x = fmaf(xa.y, w1.x, acc0.x); acc0.y = fmaf(xa.y, w1.y, acc0.y);
        acc0.z = fmaf(xa.y, w1.z, acc0.z); acc0.w = fmaf(xa.y, w1.w, acc0.w);
        acc0.x = fmaf(xa.z, w2.x, acc0.x); acc0.y = fmaf(xa.z, w2.y, acc0.y);
        acc0.z = fmaf(xa.z, w2.z, acc0.z); acc0.w = fmaf(xa.z, w2.w, acc0.w);
        acc0.x = fmaf(xa.w, w3.x, acc0.x); acc0.y = fmaf(xa.w, w3.y, acc0.y);
        acc0.z = fmaf(xa.w, w3.z, acc0.z); acc0.w = fmaf(xa.w, w3.w, acc0.w);
        acc1.x = fmaf(xb.x, w0.x, acc1.x); acc1.y = fmaf(xb.x, w0.y, acc1.y);
        acc1.z = fmaf(xb.x, w0.z, acc1.z); acc1.w = fmaf(xb.x, w0.w, acc1.w);
        acc1.x = fmaf(xb.y, w1.x, acc1.x); acc1.y = fmaf(xb.y, w1.y, acc1.y);
        acc1.z = fmaf(xb.y, w1.z, acc1.z); acc1.w = fmaf(xb.y, w1.w, acc1.w);
        acc1.x = fmaf(xb.z, w2.x, acc1.x); acc1.y = fmaf(xb.z, w2.y, acc1.y);
        acc1.z = fmaf(xb.z, w2.z, acc1.z); acc1.w = fmaf(xb.z, w2.w, acc1.w);
        acc1.x = fmaf(xb.w, w3.x, acc1.x); acc1.y = fmaf(xb.w, w3.y, acc1.y);
        acc1.z = fmaf(xb.w, w3.z, acc1.z); acc1.w = fmaf(xb.w, w3.w, acc1.w);
    }

    const float4 bv = *(const float4*)(bf + f0);
    float4 s0, s1;
    s0.x = fast_sigmoid_from_t(__expf(-(acc0.x + bv.x)));
    s0.y = fast_sigmoid_from_t(__expf(-(acc0.y + bv.y)));
    s0.z = fast_sigmoid_from_t(__expf(-(acc0.z + bv.z)));
    s0.w = fast_sigmoid_from_t(__expf(-(acc0.w + bv.w)));
    s1.x = fast_sigmoid_from_t(__expf(-(acc1.x + bv.x)));
    s1.y = fast_sigmoid_from_t(__expf(-(acc1.y + bv.y)));
    s1.z = fast_sigmoid_from_t(__expf(-(acc1.z + bv.z)));
    s1.w = fast_sigmoid_from_t(__expf(-(acc1.w + bv.w)));

    __syncthreads();   // all GEMM reads of x done before overwriting with s
    *(float4*)&xs[r0 * XS_STRIDE + f0] = s0;
    *(float4*)&xs[(r0 + 1) * XS_STRIDE + f0] = s1;
    __syncthreads();

    // ---- edge sums via telescoped exp chain ----
    // thread = (feat, edge-group). eg sizes: 9,8,8,8 (edges 0..32).
    const int feat = t & 127;
    const int eg = t >> 7;                         // wave-uniform
    const int estart = (eg == 0) ? 0 : eg * 8 + 1; // 0,9,17,25
    const int ne = (eg == 0) ? 9 : 8;
    const float c0 = 3.125f * (float)estart;

    float locE[9];
    #pragma unroll
    for (int j = 0; j < 9; ++j) locE[j] = 0.f;

    for (int r = 0; r < K1_ROWS; ++r) {
        const float s = xs[r * XS_STRIDE + feat];   // 2-way bank alias: free
        // t_j = e^{3.125*(estart+j) - 100 s}; monotone increasing in j, so
        // flush-to-0 at the start and inf at the end both give correct sigma.
        float tt = __expf(c0 - 100.f * s);
        #pragma unroll
        for (int j = 0; j < 9; ++j) {
            locE[j] += fast_sigmoid_from_t(tt);
            tt *= EXP_3_125;
        }
    }

    float* dst = E_part + (size_t)blk * CELLS + feat * NEDGE + estart;
    for (int j = 0; j < ne; ++j) dst[j] = locE[j];  // L2 merges scattered 4B
}

// ---------------------------------------------------------------------------
// K3: reduce E_part -> 17 edge cells for this block's 16 hist rows, then
//     h1_part[b][:] = hist[b*16 .. b*16+16) @ W1 rows. W1 prefetched into
//     registers BEFORE the reduce to hide its HBM latency.
// ---------------------------------------------------------------------------
__global__ __launch_bounds__(256) void k3_h1(
    const float* __restrict__ E_part, const float* __restrict__ W1,
    float* __restrict__ h1_part)
{
    const int b = blockIdx.x, t = threadIdx.x;
    const int f = b >> 1, bin0 = (b & 1) * 16;
    const int c0 = f * NEDGE + bin0;

    // prefetch 16 rows of W1 (cols 4t..4t+3)
    float4 w[16];
    #pragma unroll
    for (int k = 0; k < 16; ++k)
        w[k] = *(const float4*)(W1 + (size_t)(b * 16 + k) * H1 + t * 4);

    __shared__ float Ered[8 * 17];
    __shared__ float hl[17];
    const int cw = t & 31, g = t >> 5;   // 8 partial-groups of 64
    if (cw < 17) {
        const float* p0 = E_part + (size_t)(g * 64) * CELLS + c0 + cw;
        float a0 = 0, a1 = 0, a2 = 0, a3 = 0;
        #pragma unroll 4
        for (int p = 0; p < 64; p += 4) {
            a0 += p0[(size_t)(p + 0) * CELLS];
            a1 += p0[(size_t)(p + 1) * CELLS];
            a2 += p0[(size_t)(p + 2) * CELLS];
            a3 += p0[(size_t)(p + 3) * CELLS];
        }
        Ered[g * 17 + cw] = (a0 + a1) + (a2 + a3);
    }
    __syncthreads();
    if (t < 17) {
        float s = 0.f;
        #pragma unroll
        for (int g2 = 0; g2 < 8; ++g2) s += Ered[g2 * 17 + t];
        hl[t] = s;
    }
    __syncthreads();

    float4 acc = {0,0,0,0};
    #pragma unroll
    for (int k = 0; k < 16; ++k) {
        const float h = (hl[k] - hl[k + 1]) * (1.f / (float)N_SAMP);
        acc.x = fmaf(h, w[k].x, acc.x);
        acc.y = fmaf(h, w[k].y, acc.y);
        acc.z = fmaf(h, w[k].z, acc.z);
        acc.w = fmaf(h, w[k].w, acc.w);
    }
    *(float4*)(h1_part + (size_t)b * H1 + t * 4) = acc;
}

// ---------------------------------------------------------------------------
// K5: finalize h1 (reduce 256 partials + b1 + leaky) for this block's 8 h1
//     entries, then h2_part[b][:] = h1[b*8..b*8+8) @ W2 rows. W2 prefetched.
// ---------------------------------------------------------------------------
__global__ __launch_bounds__(128) void k5_h2(
    const float* __restrict__ h1_part, const float* __restrict__ b1,
    const float* __restrict__ W2, float* __restrict__ h2_part)
{
    const int b = blockIdx.x, t = threadIdx.x;   // 128 blocks x 128 thr

    float4 w[8];
    #pragma unroll
    for (int k = 0; k < 8; ++k)
        w[k] = *(const float4*)(W2 + (size_t)(b * 8 + k) * H2 + t * 4);

    __shared__ float hred[8 * 16];
    __shared__ float hv[8];
    const int col = t & 7, q = t >> 3;   // 16 partial-groups of 16
    {
        const float* p0 = h1_part + (size_t)(q * 16) * H1 + b * 8 + col;
        float a0 = 0, a1 = 0, a2 = 0, a3 = 0;
        #pragma unroll
        for (int p = 0; p < 16; p += 4) {
            a0 += p0[(size_t)(p + 0) * H1];
            a1 += p0[(size_t)(p + 1) * H1];
            a2 += p0[(size_t)(p + 2) * H1];
            a3 += p0[(size_t)(p + 3) * H1];
        }
        hred[col * 16 + q] = (a0 + a1) + (a2 + a3);
    }
    __syncthreads();
    if (t < 8) {
        float s = 0.f;
        #pragma unroll
        for (int q2 = 0; q2 < 16; ++q2) s += hred[t * 16 + q2];
        hv[t] = lrelu(s + b1[b * 8 + t]);
    }
    __syncthreads();

    float4 acc = {0,0,0,0};
    #pragma unroll
    for (int k = 0; k < 8; ++k) {
        const float h = hv[k];
        acc.x = fmaf(h, w[k].x, acc.x);
        acc.y = fmaf(h, w[k].y, acc.y);
        acc.z = fmaf(h, w[k].z, acc.z);
        acc.w = fmaf(h, w[k].w, acc.w);
    }
    *(float4*)(h2_part + (size_t)b * H2 + t * 4) = acc;
}

// ---------------------------------------------------------------------------
// K6: finalize h2 (reduce 128 partials + b2 + leaky), logits = h2@W3 + b3,
//     softmax -> out[10]. Single block of 512.
// ---------------------------------------------------------------------------
__global__ __launch_bounds__(512) void k6_final(
    const float* __restrict__ h2_part, const float* __restrict__ b2,
    const float* __restrict__ W3, const float* __restrict__ b3,
    float* __restrict__ out)
{
    const int t = threadIdx.x;
    float a0 = 0, a1 = 0, a2 = 0, a3 = 0;
    #pragma unroll 8
    for (int p = 0; p < 128; p += 4) {
        a0 += h2_part[(size_t)(p + 0) * H2 + t];
        a1 += h2_part[(size_t)(p + 1) * H2 + t];
        a2 += h2_part[(size_t)(p + 2) * H2 + t];
        a3 += h2_part[(size_t)(p + 3) * H2 + t];
    }
    const float h2v = lrelu(((a0 + a1) + (a2 + a3)) + b2[t]);

    float lc[NC];
    #pragma unroll
    for (int c = 0; c < NC; ++c) lc[c] = h2v * W3[t * NC + c];
    #pragma unroll
    for (int off = 32; off >= 1; off >>= 1) {
        #pragma unroll
        for (int c = 0; c < NC; ++c) lc[c] += __shfl_down(lc[c], off, 64);
    }

    __shared__ float wsum[8][NC];
    if ((t & 63) == 0) {
        #pragma unroll
        for (int c = 0; c < NC; ++c) wsum[t >> 6][c] = lc[c];
    }
    __syncthreads();

    if (t == 0) {
        float logits[NC];
        float m = -1e30f;
        #pragma unroll
        for (int c = 0; c < NC; ++c) {
            float v = b3[c];
            for (int ww = 0; ww < 8; ++ww) v += wsum[ww][c];
            logits[c] = v;
            m = fmaxf(m, v);
        }
        float ssum = 0.f;
        #pragma unroll
        for (int c = 0; c < NC; ++c) { logits[c] = __expf(logits[c] - m); ssum += logits[c]; }
        const float inv = 1.f / ssum;
        #pragma unroll
        for (int c = 0; c < NC; ++c) out[c] = logits[c] * inv;
    }
}

extern "C" void kernel_launch(void* const* d_in, const int* in_sizes, int n_in,
                              void* d_out, int out_size, void* d_ws, size_t ws_size,
                              hipStream_t stream)
{
    const float* x  = (const float*)d_in[0];
    const float* Wf = (const float*)d_in[1];
    const float* bf = (const float*)d_in[2];
    const float* W1 = (const float*)d_in[3];
    const float* b1 = (const float*)d_in[4];
    const float* W2 = (const float*)d_in[5];
    const float* b2 = (const float*)d_in[6];
    const float* W3 = (const float*)d_in[7];
    const float* b3 = (const float*)d_in[8];
    float* out = (float*)d_out;

    float* ws      = (float*)d_ws;
    float* E_part  = ws;                                        // 512*4224 = 2.16M f (8.65 MB)
    float* h1_part = E_part + (size_t)K1_BLOCKS * CELLS;        // 256*1024 f (1 MB)
    float* h2_part = h1_part + (size_t)K3_BLOCKS * H1;          // 128*512 f (0.25 MB)

    k1_feat_hist<<<K1_BLOCKS, K1_THREADS, 0, stream>>>(x, Wf, bf, E_part);
    k3_h1<<<K3_BLOCKS, 256, 0, stream>>>(E_part, W1, h1_part);
    k5_h2<<<128, 128, 0, stream>>>(h1_part, b1, W2, h2_part);
    k6_final<<<1, 512, 0, stream>>>(h2_part, b2, W3, b3, out);
}